// Round 7
// baseline (80.683 us; speedup 1.0000x reference)
//
#include <hip/hip_runtime.h>
#include <math.h>

#define POOL 7
#define NUM_ROIS 300
#define FH 50
#define FW 50
#define FC 512
#define NBINS (POOL * POOL)                    // 49 bins per ROI
#define ROW_F4 (POOL * FC / 4)                 // 896 float4 per (roi,row-bin)

typedef float floatx4 __attribute__((ext_vector_type(4)));  // native vec for nontemporal

// Single fused launch: one block per (roi, row-bin) = 2100 blocks x 256 thr.
// Phase 1: channel-max for ONLY this block's slice (<=8 rows x <=50 cols of
//          the ROI rect; rows of a ROI are partitioned across its 7 row-bin
//          blocks, so no straggler like R4's per-ROI fusion). 16 groups of
//          16 lanes; each group reduces one pixel (8 independent float4
//          loads/lane, 4-step shfl_xor). fm = 5.12 MB -> L2/L3-resident.
// Phase 2: lanes 0..6 compute the 7 col-bin maxima from LDS.
// Phase 3: 896 balanced nontemporal float4 stores (30 MB aggregate = floor).
__global__ __launch_bounds__(256) void roi_row_fused(
    const float* __restrict__ rois, const float* __restrict__ fm,
    float* __restrict__ out) {
    __shared__ float srow[8 * FW];              // <=8 rows x <=50 cols
    __shared__ float pooled[POOL];
    int b = blockIdx.x;
    int n = b / POOL;                           // roi
    int i = b - n * POOL;                       // row bin
    int t = threadIdx.x;

    // Replicate: r = int32(roi * (1/16)) (truncation; values non-negative).
    int x1 = (int)(rois[n * 5 + 1] * 0.0625f);
    int y1 = (int)(rois[n * 5 + 2] * 0.0625f);
    int x2 = (int)(rois[n * 5 + 3] * 0.0625f);
    int y2 = (int)(rois[n * 5 + 4] * 0.0625f);
    int rh = y2 - y1 + 1;
    int rw = x2 - x1 + 1;

    // This block's row range (Python floor-div on non-neg == C int div).
    int hs = min(max(y1 + (i * rh) / POOL, 0), FH);
    int he = min(max(y1 + ((i + 1) * rh + POOL - 1) / POOL, 0), FH);
    // Union of all 7 col-bins: [x1, min(x1+rw, FW))  (x1 <= 25 < FW always).
    int cs = min(max(x1, 0), FW);
    int ce = min(max(x1 + rw, 0), FW);
    int nrow = he - hs, ncol = ce - cs;
    int npix = nrow * ncol;                     // <= 8*50 = 400

    // Phase 1: group g handles pixels g, g+16, ... of the slice.
    int grp = t >> 4, gl = t & 15;
    for (int p = grp; p < npix; p += 16) {
        int ph = p / ncol;                      // group-uniform small div
        int pw = p - ph * ncol;
        const float4* q =
            (const float4*)(fm + (size_t)((hs + ph) * FW + (cs + pw)) * FC);
        float m = -INFINITY;
        #pragma unroll
        for (int r = 0; r < 8; ++r) {           // 8 independent 16B loads
            float4 v = q[gl + 16 * r];
            m = fmaxf(m, fmaxf(fmaxf(v.x, v.y), fmaxf(v.z, v.w)));
        }
        #pragma unroll
        for (int off = 8; off > 0; off >>= 1)   // reduce across 16-lane group
            m = fmaxf(m, __shfl_xor(m, off, 64));
        if (gl == 0) srow[p] = m;
    }
    __syncthreads();

    // Phase 2: col-bin maxima for this row-bin.
    if (t < POOL) {
        int j = t;                              // col bin
        int ws = min(max(x1 + (j * rw) / POOL, 0), FW);
        int we = min(max(x1 + ((j + 1) * rw + POOL - 1) / POOL, 0), FW);
        float m = -INFINITY;                    // empty bin -> -inf (matches ref)
        for (int h = hs; h < he; ++h)           // [ws,we) subset of [cs,ce)
            for (int w = ws; w < we; ++w)
                m = fmaxf(m, srow[(h - hs) * ncol + (w - cs)]);
        pooled[t] = m;
    }
    __syncthreads();

    // Phase 3: this (roi,row-bin)'s 7*512 floats = 896 float4; col bin = f>>7.
    floatx4* o4 = (floatx4*)(out + ((size_t)n * NBINS + (size_t)i * POOL) * FC);
    for (int f = t; f < ROW_F4; f += 256) {
        float m = pooled[f >> 7];
        floatx4 v = {m, m, m, m};
        __builtin_nontemporal_store(v, &o4[f]);
    }
}

extern "C" void kernel_launch(void* const* d_in, const int* in_sizes, int n_in,
                              void* d_out, int out_size, void* d_ws, size_t ws_size,
                              hipStream_t stream) {
    const float* rois = (const float*)d_in[0];          // (300, 5) f32
    const float* feature_maps = (const float*)d_in[1];  // (50, 50, 512) f32
    float* out = (float*)d_out;                         // (300, 7, 7, 512) f32
    (void)d_ws; (void)ws_size;                          // workspace unused

    roi_row_fused<<<NUM_ROIS * POOL, 256, 0, stream>>>(rois, feature_maps, out);
}